// Round 2
// baseline (573.706 us; speedup 1.0000x reference)
//
#include <hip/hip_runtime.h>

// MHA forward: B=2, S=4096, H=12, HD=64, D=768. f32 in/out, bf16 MFMA compute.
// Pipeline: cvt(x,W)->bf16 | GEMM qkv (M8192,N2304,K768) -> Q,K,V [B,H,S,64]
//           | flash attn -> ctx [B,S,768] bf16 | GEMM out (M8192,N768,K768) -> f32.

#define S_LEN 4096
#define NHEAD 12
#define NEGINF_SCORE (-1e9f)

typedef __attribute__((ext_vector_type(8))) short short8;
typedef __attribute__((ext_vector_type(4))) float f32x4;

__device__ __forceinline__ unsigned short f2bf(float f) {
  unsigned u = __builtin_bit_cast(unsigned, f);
  u += 0x7fffu + ((u >> 16) & 1u);   // round-to-nearest-even
  return (unsigned short)(u >> 16);
}

__device__ __forceinline__ f32x4 mfma_bf16(short8 a, short8 b, f32x4 c) {
  return __builtin_amdgcn_mfma_f32_16x16x32_bf16(a, b, c, 0, 0, 0);
}

// ---------------- f32 -> bf16 convert, 8 elems/thread ----------------
__global__ __launch_bounds__(256) void cvt_kernel(const float* __restrict__ in,
                                                  unsigned short* __restrict__ out,
                                                  int n8) {
  int i = blockIdx.x * blockDim.x + threadIdx.x;
  int stride = gridDim.x * blockDim.x;
  for (; i < n8; i += stride) {
    float4 a = ((const float4*)in)[i * 2];
    float4 b = ((const float4*)in)[i * 2 + 1];
    short8 r;
    r[0] = (short)f2bf(a.x); r[1] = (short)f2bf(a.y);
    r[2] = (short)f2bf(a.z); r[3] = (short)f2bf(a.w);
    r[4] = (short)f2bf(b.x); r[5] = (short)f2bf(b.y);
    r[6] = (short)f2bf(b.z); r[7] = (short)f2bf(b.w);
    ((short8*)out)[i] = r;
  }
}

// ---------------- GEMM: C = A * Bm^T (+bias). 128x128 tile, BK=32 ----------------
// A [M][K] bf16 row-major, Bm [N][K] bf16 row-major (torch Linear weight).
// EPI=0: scatter to q/k/v [B,H,S,64] bf16 (qkv contiguous). EPI=1: f32 out + bias.
template <int EPI>
__global__ __launch_bounds__(256)
void gemm_bt(const unsigned short* __restrict__ A, const unsigned short* __restrict__ Bm,
             int K,
             const float* __restrict__ bias0, const float* __restrict__ bias1,
             const float* __restrict__ bias2,
             unsigned short* __restrict__ qkv_out, float* __restrict__ f_out) {
  __shared__ short As[128][40];  // +8 pad: row stride 80B -> ds_read_b128 ~conflict-free
  __shared__ short Bs[128][40];
  const int n0 = blockIdx.x * 128;
  const int m0 = blockIdx.y * 128;
  const int t = threadIdx.x;
  const int lane = t & 63;
  const int w = t >> 6, wm = w >> 1, wn = w & 1;  // 2x2 waves, 64x64 out each
  const int sr = t >> 2, sc = (t & 3) * 8;        // staging: row, col(8-elem chunk)
  const unsigned short* ga = A + (m0 + sr) * K + sc;
  const unsigned short* gb = Bm + (n0 + sr) * K + sc;
  f32x4 acc[4][4] = {};
  for (int kt = 0; kt < K; kt += 32) {
    short8 a0 = *(const short8*)(ga + kt);
    short8 a1 = *(const short8*)(ga + kt + 64 * K);
    short8 b0 = *(const short8*)(gb + kt);
    short8 b1 = *(const short8*)(gb + kt + 64 * K);
    __syncthreads();  // prev iter's frag reads done before overwrite
    *(short8*)&As[sr][sc] = a0;
    *(short8*)&As[sr + 64][sc] = a1;
    *(short8*)&Bs[sr][sc] = b0;
    *(short8*)&Bs[sr + 64][sc] = b1;
    __syncthreads();
    short8 af[4], bfr[4];
#pragma unroll
    for (int i = 0; i < 4; i++) {
      af[i]  = *(const short8*)&As[wm * 64 + i * 16 + (lane & 15)][(lane >> 4) * 8];
      bfr[i] = *(const short8*)&Bs[wn * 64 + i * 16 + (lane & 15)][(lane >> 4) * 8];
    }
#pragma unroll
    for (int mi = 0; mi < 4; mi++)
#pragma unroll
      for (int ni = 0; ni < 4; ni++)
        acc[mi][ni] = mfma_bf16(af[mi], bfr[ni], acc[mi][ni]);
  }
  // C/D frag layout: row=(lane>>4)*4+reg, col=lane&15 (learn_hip m89)
  if constexpr (EPI == 0) {
    const int tix = n0 / 768;  // 0=q 1=k 2=v (128 | 768 so uniform per block)
    const float* bias = (tix == 0) ? bias0 : (tix == 1) ? bias1 : bias2;
    unsigned short* dst = qkv_out + tix * (2 * NHEAD * S_LEN * 64);
#pragma unroll
    for (int mi = 0; mi < 4; mi++) {
      const int r0 = m0 + wm * 64 + mi * 16 + ((lane >> 4) << 2);
#pragma unroll
      for (int ni = 0; ni < 4; ni++) {
        const int jr = (n0 - tix * 768) + wn * 64 + ni * 16 + (lane & 15);
        const int h = jr >> 6, d = jr & 63;
        const float bv = bias[jr];
#pragma unroll
        for (int reg = 0; reg < 4; reg++) {
          const int r = r0 + reg;
          const int b = r >> 12, s = r & (S_LEN - 1);
          dst[(((b * NHEAD + h) * S_LEN + s) << 6) + d] = f2bf(acc[mi][ni][reg] + bv);
        }
      }
    }
  } else {
#pragma unroll
    for (int mi = 0; mi < 4; mi++) {
      const int r0 = m0 + wm * 64 + mi * 16 + ((lane >> 4) << 2);
#pragma unroll
      for (int ni = 0; ni < 4; ni++) {
        const int gc = n0 + wn * 64 + ni * 16 + (lane & 15);
        const float bv = bias0[gc];
#pragma unroll
        for (int reg = 0; reg < 4; reg++)
          f_out[(r0 + reg) * 768 + gc] = acc[mi][ni][reg] + bv;
      }
    }
  }
}

// ---------------- flash attention ----------------
// grid (S/128, B*H), 256 thr = 4 waves; wave owns 32 q-rows. KV tile = 64.
__global__ __launch_bounds__(256)
void attn_kernel(const unsigned short* __restrict__ Q, const unsigned short* __restrict__ Km,
                 const unsigned short* __restrict__ V, const int* __restrict__ mask,
                 unsigned short* __restrict__ ctx) {
  __shared__ short Ks[64][72];   // [key][d]  (+8 pad)
  __shared__ short Vt[64][72];   // [d][key]  transposed at stage time
  __shared__ short Ps[128][72];  // [q_local][key] P tile for PV A-operand
  const int qt = blockIdx.x;
  const int bh = blockIdx.y;
  const int b = bh / NHEAD, h = bh % NHEAD;
  const unsigned short* Qb = Q + bh * (S_LEN * 64);
  const unsigned short* Kb = Km + bh * (S_LEN * 64);
  const unsigned short* Vb = V + bh * (S_LEN * 64);
  const int* mb = mask + b * S_LEN;
  const int t = threadIdx.x, lane = t & 63, w = t >> 6;
  const int q0 = qt * 128 + w * 32;
  // Q fragments in registers: A[m=q][k=d], row=lane&15, d=(lane>>4)*8 (+32 for ks=1)
  short8 qf[2][2];
#pragma unroll
  for (int mi = 0; mi < 2; mi++)
#pragma unroll
    for (int ks = 0; ks < 2; ks++)
      qf[mi][ks] = *(const short8*)(Qb + (q0 + mi * 16 + (lane & 15)) * 64 +
                                    ks * 32 + (lane >> 4) * 8);
  f32x4 oacc[2][4] = {};
  float mrun[2][4], lrun[2][4];
#pragma unroll
  for (int mi = 0; mi < 2; mi++)
#pragma unroll
    for (int r = 0; r < 4; r++) { mrun[mi][r] = -__builtin_inff(); lrun[mi][r] = 0.f; }

  // staging: FULL 64x64 tile. sr in [0,32), sc in [0,64); each thread does
  // rows sr and sr+32 of both K and V (16 elems each buffer).
  const int sr = t >> 3, sc = (t & 7) * 8;
  for (int k0 = 0; k0 < S_LEN; k0 += 64) {
    // issue global loads before barrier: overlap with previous tile's PV
    short8 kv0 = *(const short8*)(Kb + (k0 + sr) * 64 + sc);
    short8 kv1 = *(const short8*)(Kb + (k0 + sr + 32) * 64 + sc);
    short8 vv0 = *(const short8*)(Vb + (k0 + sr) * 64 + sc);
    short8 vv1 = *(const short8*)(Vb + (k0 + sr + 32) * 64 + sc);
    __syncthreads();
    *(short8*)&Ks[sr][sc] = kv0;
    *(short8*)&Ks[sr + 32][sc] = kv1;
#pragma unroll
    for (int j = 0; j < 8; j++) {
      Vt[sc + j][sr] = vv0[j];        // scalar transpose (baseline)
      Vt[sc + j][sr + 32] = vv1[j];
    }
    __syncthreads();
    // S = Q K^T : B[kdim=d][n=key] read from Ks[key][d]
    f32x4 sf[2][4];
#pragma unroll
    for (int ni = 0; ni < 4; ni++) {
      short8 kf0 = *(const short8*)&Ks[ni * 16 + (lane & 15)][(lane >> 4) * 8];
      short8 kf1 = *(const short8*)&Ks[ni * 16 + (lane & 15)][32 + (lane >> 4) * 8];
#pragma unroll
      for (int mi = 0; mi < 2; mi++) {
        f32x4 z = {0.f, 0.f, 0.f, 0.f};
        z = mfma_bf16(qf[mi][0], kf0, z);
        z = mfma_bf16(qf[mi][1], kf1, z);
        sf[mi][ni] = z;
      }
    }
    // scale + mask (reference: scores/8 then where(mask==0, -1e9))
    int mk[4];
#pragma unroll
    for (int ni = 0; ni < 4; ni++) mk[ni] = mb[k0 + ni * 16 + (lane & 15)];
#pragma unroll
    for (int mi = 0; mi < 2; mi++)
#pragma unroll
      for (int ni = 0; ni < 4; ni++)
#pragma unroll
        for (int r = 0; r < 4; r++) {
          float s = sf[mi][ni][r] * 0.125f;
          sf[mi][ni][r] = (mk[ni] == 0) ? NEGINF_SCORE : s;
        }
    // online softmax; row r of frag lives in the 16-lane group (same lane>>4)
#pragma unroll
    for (int mi = 0; mi < 2; mi++)
#pragma unroll
      for (int r = 0; r < 4; r++) {
        float mx = fmaxf(fmaxf(sf[mi][0][r], sf[mi][1][r]),
                         fmaxf(sf[mi][2][r], sf[mi][3][r]));
#pragma unroll
        for (int off = 1; off < 16; off <<= 1) mx = fmaxf(mx, __shfl_xor(mx, off, 64));
        float mnew = fmaxf(mrun[mi][r], mx);
        float alpha = __expf(mrun[mi][r] - mnew);
        mrun[mi][r] = mnew;
        float ps = 0.f;
#pragma unroll
        for (int ni = 0; ni < 4; ni++) {
          float p = __expf(sf[mi][ni][r] - mnew);
          sf[mi][ni][r] = p;
          ps += p;
        }
#pragma unroll
        for (int off = 1; off < 16; off <<= 1) ps += __shfl_xor(ps, off, 64);
        lrun[mi][r] = lrun[mi][r] * alpha + ps;
#pragma unroll
        for (int dj = 0; dj < 4; dj++) oacc[mi][dj][r] *= alpha;
      }
    // P -> LDS (bf16) in [q][key] layout for PV A-fragments
#pragma unroll
    for (int mi = 0; mi < 2; mi++)
#pragma unroll
      for (int ni = 0; ni < 4; ni++)
#pragma unroll
        for (int r = 0; r < 4; r++)
          Ps[w * 32 + mi * 16 + (lane >> 4) * 4 + r][ni * 16 + (lane & 15)] =
              (short)f2bf(sf[mi][ni][r]);
    __syncthreads();
    // O += P V : A from Ps, B[kdim=key][n=d] from Vt[d][key]
#pragma unroll
    for (int kk = 0; kk < 2; kk++) {
      short8 pf[2];
#pragma unroll
      for (int mi = 0; mi < 2; mi++)
        pf[mi] = *(const short8*)&Ps[w * 32 + mi * 16 + (lane & 15)][kk * 32 + (lane >> 4) * 8];
#pragma unroll
      for (int dj = 0; dj < 4; dj++) {
        short8 vf = *(const short8*)&Vt[dj * 16 + (lane & 15)][kk * 32 + (lane >> 4) * 8];
#pragma unroll
        for (int mi = 0; mi < 2; mi++)
          oacc[mi][dj] = mfma_bf16(pf[mi], vf, oacc[mi][dj]);
      }
    }
  }
  // ctx[b][s][h*64+d] bf16
#pragma unroll
  for (int mi = 0; mi < 2; mi++)
#pragma unroll
    for (int r = 0; r < 4; r++) {
      const int qrow = q0 + mi * 16 + (lane >> 4) * 4 + r;
      const float inv = 1.f / lrun[mi][r];
#pragma unroll
      for (int dj = 0; dj < 4; dj++) {
        const int d = dj * 16 + (lane & 15);
        ctx[(b * S_LEN + qrow) * 768 + h * 64 + d] = f2bf(oacc[mi][dj][r] * inv);
      }
    }
}

// ---------------- launch ----------------
extern "C" void kernel_launch(void* const* d_in, const int* in_sizes, int n_in,
                              void* d_out, int out_size, void* d_ws, size_t ws_size,
                              hipStream_t stream) {
  const float* x  = (const float*)d_in[0];
  const int* mask = (const int*)d_in[1];
  const float* Wq = (const float*)d_in[2];
  const float* bq = (const float*)d_in[3];
  const float* Wk = (const float*)d_in[4];
  const float* bk = (const float*)d_in[5];
  const float* Wv = (const float*)d_in[6];
  const float* bv = (const float*)d_in[7];
  const float* Wo = (const float*)d_in[8];
  const float* bo = (const float*)d_in[9];
  float* out = (float*)d_out;

  const int NE = 8192 * 768;  // 6291456 elements (= B*S*D = B*H*S*HD)
  const int WE = 768 * 768;
  unsigned short* ws   = (unsigned short*)d_ws;  // total used: ~67.6 MB
  unsigned short* xb   = ws;               // x bf16 [8192][768]
  unsigned short* wqkv = xb + NE;          // [2304][768] = Wq|Wk|Wv rows
  unsigned short* wob  = wqkv + 3 * WE;    // [768][768]
  unsigned short* qb   = wob + WE;         // Q|K|V each [24][4096][64], contiguous
  unsigned short* ctxb = qb + 3 * NE;      // ctx bf16 [8192][768]

  cvt_kernel<<<dim3(2048), 256, 0, stream>>>(x, xb, NE / 8);
  cvt_kernel<<<dim3(288), 256, 0, stream>>>(Wq, wqkv, WE / 8);
  cvt_kernel<<<dim3(288), 256, 0, stream>>>(Wk, wqkv + WE, WE / 8);
  cvt_kernel<<<dim3(288), 256, 0, stream>>>(Wv, wqkv + 2 * WE, WE / 8);
  cvt_kernel<<<dim3(288), 256, 0, stream>>>(Wo, wob, WE / 8);

  gemm_bt<0><<<dim3(18, 64), 256, 0, stream>>>(xb, wqkv, 768, bq, bk, bv, qb, nullptr);
  attn_kernel<<<dim3(32, 24), 256, 0, stream>>>(qb, qb + NE, qb + 2 * NE, mask, ctxb);
  gemm_bt<1><<<dim3(6, 64), 256, 0, stream>>>(ctxb, wob, 768, bo, nullptr, nullptr,
                                              nullptr, out);
}

// Round 3
// 404.506 us; speedup vs baseline: 1.4183x; 1.4183x over previous
//
#include <hip/hip_runtime.h>

// MHA forward: B=2, S=4096, H=12, HD=64, D=768. f32 in/out, bf16 MFMA compute.
// Pipeline: cvt(x,W)->bf16 | GEMM qkv (M8192,N2304,K768) -> Q,K,V [B,H,S,64]
//           | flash attn (swapped-QK^T, in-register softmax) -> ctx bf16
//           | GEMM out (M8192,N768,K768) -> f32.

#define S_LEN 4096
#define NHEAD 12
#define NEGINF_SCORE (-1e9f)

typedef __attribute__((ext_vector_type(8))) short short8;
typedef __attribute__((ext_vector_type(4))) float f32x4;
typedef __attribute__((ext_vector_type(4))) int i32x4;

__device__ __forceinline__ unsigned short f2bf(float f) {
  unsigned u = __builtin_bit_cast(unsigned, f);
  u += 0x7fffu + ((u >> 16) & 1u);   // round-to-nearest-even
  return (unsigned short)(u >> 16);
}

__device__ __forceinline__ f32x4 mfma_bf16(short8 a, short8 b, f32x4 c) {
  return __builtin_amdgcn_mfma_f32_16x16x32_bf16(a, b, c, 0, 0, 0);
}

// ---------------- f32 -> bf16 convert, 8 elems/thread ----------------
__global__ __launch_bounds__(256) void cvt_kernel(const float* __restrict__ in,
                                                  unsigned short* __restrict__ out,
                                                  int n8) {
  int i = blockIdx.x * blockDim.x + threadIdx.x;
  int stride = gridDim.x * blockDim.x;
  for (; i < n8; i += stride) {
    float4 a = ((const float4*)in)[i * 2];
    float4 b = ((const float4*)in)[i * 2 + 1];
    short8 r;
    r[0] = (short)f2bf(a.x); r[1] = (short)f2bf(a.y);
    r[2] = (short)f2bf(a.z); r[3] = (short)f2bf(a.w);
    r[4] = (short)f2bf(b.x); r[5] = (short)f2bf(b.y);
    r[6] = (short)f2bf(b.z); r[7] = (short)f2bf(b.w);
    ((short8*)out)[i] = r;
  }
}

// ---------------- GEMM: C = A * Bm^T (+bias). 128x128 tile, BK=32 ----------------
template <int EPI>
__global__ __launch_bounds__(256)
void gemm_bt(const unsigned short* __restrict__ A, const unsigned short* __restrict__ Bm,
             int K,
             const float* __restrict__ bias0, const float* __restrict__ bias1,
             const float* __restrict__ bias2,
             unsigned short* __restrict__ qkv_out, float* __restrict__ f_out) {
  __shared__ short As[128][40];
  __shared__ short Bs[128][40];
  const int n0 = blockIdx.x * 128;
  const int m0 = blockIdx.y * 128;
  const int t = threadIdx.x;
  const int lane = t & 63;
  const int w = t >> 6, wm = w >> 1, wn = w & 1;
  const int sr = t >> 2, sc = (t & 3) * 8;
  const unsigned short* ga = A + (m0 + sr) * K + sc;
  const unsigned short* gb = Bm + (n0 + sr) * K + sc;
  f32x4 acc[4][4] = {};
  for (int kt = 0; kt < K; kt += 32) {
    short8 a0 = *(const short8*)(ga + kt);
    short8 a1 = *(const short8*)(ga + kt + 64 * K);
    short8 b0 = *(const short8*)(gb + kt);
    short8 b1 = *(const short8*)(gb + kt + 64 * K);
    __syncthreads();
    *(short8*)&As[sr][sc] = a0;
    *(short8*)&As[sr + 64][sc] = a1;
    *(short8*)&Bs[sr][sc] = b0;
    *(short8*)&Bs[sr + 64][sc] = b1;
    __syncthreads();
    short8 af[4], bfr[4];
#pragma unroll
    for (int i = 0; i < 4; i++) {
      af[i]  = *(const short8*)&As[wm * 64 + i * 16 + (lane & 15)][(lane >> 4) * 8];
      bfr[i] = *(const short8*)&Bs[wn * 64 + i * 16 + (lane & 15)][(lane >> 4) * 8];
    }
#pragma unroll
    for (int mi = 0; mi < 4; mi++)
#pragma unroll
      for (int ni = 0; ni < 4; ni++)
        acc[mi][ni] = mfma_bf16(af[mi], bfr[ni], acc[mi][ni]);
  }
  if constexpr (EPI == 0) {
    const int tix = n0 / 768;
    const float* bias = (tix == 0) ? bias0 : (tix == 1) ? bias1 : bias2;
    unsigned short* dst = qkv_out + tix * (2 * NHEAD * S_LEN * 64);
#pragma unroll
    for (int mi = 0; mi < 4; mi++) {
      const int r0 = m0 + wm * 64 + mi * 16 + ((lane >> 4) << 2);
#pragma unroll
      for (int ni = 0; ni < 4; ni++) {
        const int jr = (n0 - tix * 768) + wn * 64 + ni * 16 + (lane & 15);
        const int h = jr >> 6, d = jr & 63;
        const float bv = bias[jr];
#pragma unroll
        for (int reg = 0; reg < 4; reg++) {
          const int r = r0 + reg;
          const int b = r >> 12, s = r & (S_LEN - 1);
          dst[(((b * NHEAD + h) * S_LEN + s) << 6) + d] = f2bf(acc[mi][ni][reg] + bv);
        }
      }
    }
  } else {
#pragma unroll
    for (int mi = 0; mi < 4; mi++) {
      const int r0 = m0 + wm * 64 + mi * 16 + ((lane >> 4) << 2);
#pragma unroll
      for (int ni = 0; ni < 4; ni++) {
        const int gc = n0 + wn * 64 + ni * 16 + (lane & 15);
        const float bv = bias0[gc];
#pragma unroll
        for (int reg = 0; reg < 4; reg++)
          f_out[(r0 + reg) * 768 + gc] = acc[mi][ni][reg] + bv;
      }
    }
  }
}

// ---------------- flash attention (swapped QK^T) ----------------
// grid (S/128, B*H), 256 thr = 4 waves; wave owns 32 q-rows. KV tile = 64.
// S^T = mfma(K, Q): lane holds S[key=16mi+4g+r][q=16qi+c] -> row softmax is
// in-register (15 ops) + 2 shfl_xor. P stays in regs: cvt_pk -> bpermute into
// PV B-frags. O^T = mfma(Vt, P^T). Vt writes XOR-swizzled (key^((d>>3)<<3)).
__global__ __launch_bounds__(256)
void attn_kernel(const unsigned short* __restrict__ Q, const unsigned short* __restrict__ Km,
                 const unsigned short* __restrict__ V, const int* __restrict__ mask,
                 unsigned short* __restrict__ ctx) {
  __shared__ short Ks[64][72];   // [key][d]
  __shared__ short Vt[64][72];   // [d][key^swz]
  const int qt = blockIdx.x;
  const int bh = blockIdx.y;
  const int b = bh / NHEAD, h = bh % NHEAD;
  const unsigned short* Qb = Q + bh * (S_LEN * 64);
  const unsigned short* Kb = Km + bh * (S_LEN * 64);
  const unsigned short* Vb = V + bh * (S_LEN * 64);
  const int* mb = mask + b * S_LEN;
  const int t = threadIdx.x, lane = t & 63, w = t >> 6;
  const int c = lane & 15, g = lane >> 4;
  const int q0 = qt * 128 + w * 32;

  // Q as PV/QKT B-operand: qf[qi][kk] = Q[q0+qi*16+c][kk*32+g*8 ..+8]
  short8 qf[2][2];
#pragma unroll
  for (int qi = 0; qi < 2; qi++)
#pragma unroll
    for (int kk = 0; kk < 2; kk++)
      qf[qi][kk] = *(const short8*)(Qb + (q0 + qi * 16 + c) * 64 + kk * 32 + g * 8);

  f32x4 oacc[4][2] = {};          // O^T frag: [dmi][qi], reg r -> d=16dmi+4g+r, q=16qi+c
  float mrun[2], lrun[2];
  mrun[0] = mrun[1] = -__builtin_inff();
  lrun[0] = lrun[1] = 0.f;

  const int sr = t >> 3, sc = (t & 7) * 8;   // staging: key row, d col (full 64x64)
  const int swzw = (t & 7) << 3;             // ((d>>3)&7)<<3 for Vt writes (d = sc+j)
  const int idx_a = c + 32 * (g & 1);        // bpermute sources for PV B-frag
  const int idx_b = idx_a + 16;
  const bool hi_sel = (lane >= 32);          // mi = 2kk + (g>>1)

  for (int k0 = 0; k0 < S_LEN; k0 += 64) {
    short8 kv0 = *(const short8*)(Kb + (k0 + sr) * 64 + sc);
    short8 kv1 = *(const short8*)(Kb + (k0 + sr + 32) * 64 + sc);
    short8 vv0 = *(const short8*)(Vb + (k0 + sr) * 64 + sc);
    short8 vv1 = *(const short8*)(Vb + (k0 + sr + 32) * 64 + sc);
    __syncthreads();
    *(short8*)&Ks[sr][sc] = kv0;
    *(short8*)&Ks[sr + 32][sc] = kv1;
#pragma unroll
    for (int j = 0; j < 8; j++) {
      Vt[sc + j][sr ^ swzw] = vv0[j];
      Vt[sc + j][(sr + 32) ^ swzw] = vv1[j];
    }
    __syncthreads();

    // S^T = K Q^T : A=Ks rows (key), B=qf. D[m=key][n=q].
    f32x4 st[2][4];
#pragma unroll
    for (int mi = 0; mi < 4; mi++) {
      short8 ka0 = *(const short8*)&Ks[mi * 16 + c][g * 8];
      short8 ka1 = *(const short8*)&Ks[mi * 16 + c][32 + g * 8];
#pragma unroll
      for (int qi = 0; qi < 2; qi++) {
        f32x4 z = {0.f, 0.f, 0.f, 0.f};
        z = mfma_bf16(ka0, qf[qi][0], z);
        z = mfma_bf16(ka1, qf[qi][1], z);
        st[qi][mi] = z;
      }
    }
    // scale + mask; key = k0 + 16mi + 4g + r
#pragma unroll
    for (int mi = 0; mi < 4; mi++) {
      i32x4 mk = *(const i32x4*)(mb + k0 + 16 * mi + 4 * g);
#pragma unroll
      for (int qi = 0; qi < 2; qi++)
#pragma unroll
        for (int r = 0; r < 4; r++)
          st[qi][mi][r] = (mk[r] == 0) ? NEGINF_SCORE : st[qi][mi][r] * 0.125f;
    }
    // in-register online softmax (per lane: full row slice of 16 keys; cross
    // 4-lane-group reduce via shfl_xor 16/32)
#pragma unroll
    for (int qi = 0; qi < 2; qi++) {
      float pm = st[qi][0][0];
#pragma unroll
      for (int mi = 0; mi < 4; mi++)
#pragma unroll
        for (int r = 0; r < 4; r++) pm = fmaxf(pm, st[qi][mi][r]);
      pm = fmaxf(pm, __shfl_xor(pm, 16));
      pm = fmaxf(pm, __shfl_xor(pm, 32));
      float mnew = fmaxf(mrun[qi], pm);
      float alpha = __expf(mrun[qi] - mnew);
      mrun[qi] = mnew;
      float ps = 0.f;
#pragma unroll
      for (int mi = 0; mi < 4; mi++)
#pragma unroll
        for (int r = 0; r < 4; r++) {
          float p = __expf(st[qi][mi][r] - mnew);
          st[qi][mi][r] = p;
          ps += p;
        }
      ps += __shfl_xor(ps, 16);
      ps += __shfl_xor(ps, 32);
      lrun[qi] = lrun[qi] * alpha + ps;
#pragma unroll
      for (int dmi = 0; dmi < 4; dmi++)
#pragma unroll
        for (int r = 0; r < 4; r++) oacc[dmi][qi][r] *= alpha;
    }
    // pack P to bf16 pairs: uu[qi][mi][0]=keys(r0,r1) lo/hi, [1]=keys(r2,r3)
    unsigned uu[2][4][2];
#pragma unroll
    for (int qi = 0; qi < 2; qi++)
#pragma unroll
      for (int mi = 0; mi < 4; mi++) {
        asm("v_cvt_pk_bf16_f32 %0, %1, %2"
            : "=v"(uu[qi][mi][0]) : "v"(st[qi][mi][0]), "v"(st[qi][mi][1]));
        asm("v_cvt_pk_bf16_f32 %0, %1, %2"
            : "=v"(uu[qi][mi][1]) : "v"(st[qi][mi][2]), "v"(st[qi][mi][3]));
      }
    // PV: O^T += Vt . P^T. B-frag jj -> key = 32kk+8g+jj, gathered from lanes
    // idx_a (jj0-3) / idx_b (jj4-7) at mi = 2kk + (g>>1).
#pragma unroll
    for (int kk = 0; kk < 2; kk++) {
      short8 pb[2];
#pragma unroll
      for (int qi = 0; qi < 2; qi++) {
        int a0 = __shfl((int)uu[qi][2 * kk][0], idx_a);
        int b0 = __shfl((int)uu[qi][2 * kk + 1][0], idx_a);
        int a1 = __shfl((int)uu[qi][2 * kk][1], idx_a);
        int b1 = __shfl((int)uu[qi][2 * kk + 1][1], idx_a);
        int a2 = __shfl((int)uu[qi][2 * kk][0], idx_b);
        int b2 = __shfl((int)uu[qi][2 * kk + 1][0], idx_b);
        int a3 = __shfl((int)uu[qi][2 * kk][1], idx_b);
        int b3 = __shfl((int)uu[qi][2 * kk + 1][1], idx_b);
        i32x4 dw;
        dw[0] = hi_sel ? b0 : a0;
        dw[1] = hi_sel ? b1 : a1;
        dw[2] = hi_sel ? b2 : a2;
        dw[3] = hi_sel ? b3 : a3;
        pb[qi] = __builtin_bit_cast(short8, dw);
      }
#pragma unroll
      for (int dmi = 0; dmi < 4; dmi++) {
        const int hsw = ((2 * dmi + (c >> 3)) & 7) << 3;
        short8 vf = *(const short8*)&Vt[16 * dmi + c][(32 * kk + 8 * g) ^ hsw];
        oacc[dmi][0] = mfma_bf16(vf, pb[0], oacc[dmi][0]);
        oacc[dmi][1] = mfma_bf16(vf, pb[1], oacc[dmi][1]);
      }
    }
  }
  // epilogue: O^T -> ctx[b][q][h*64+d], 8B stores (4 bf16 along d)
#pragma unroll
  for (int qi = 0; qi < 2; qi++) {
    const float inv = 1.f / lrun[qi];
    const int row = q0 + qi * 16 + c;
#pragma unroll
    for (int dmi = 0; dmi < 4; dmi++) {
      float x0 = oacc[dmi][qi][0] * inv, x1 = oacc[dmi][qi][1] * inv;
      float x2 = oacc[dmi][qi][2] * inv, x3 = oacc[dmi][qi][3] * inv;
      unsigned p0, p1;
      asm("v_cvt_pk_bf16_f32 %0, %1, %2" : "=v"(p0) : "v"(x0), "v"(x1));
      asm("v_cvt_pk_bf16_f32 %0, %1, %2" : "=v"(p1) : "v"(x2), "v"(x3));
      uint2 u2v; u2v.x = p0; u2v.y = p1;
      *(uint2*)&ctx[(size_t)(b * S_LEN + row) * 768 + h * 64 + 16 * dmi + 4 * g] = u2v;
    }
  }
}

// ---------------- launch ----------------
extern "C" void kernel_launch(void* const* d_in, const int* in_sizes, int n_in,
                              void* d_out, int out_size, void* d_ws, size_t ws_size,
                              hipStream_t stream) {
  const float* x  = (const float*)d_in[0];
  const int* mask = (const int*)d_in[1];
  const float* Wq = (const float*)d_in[2];
  const float* bq = (const float*)d_in[3];
  const float* Wk = (const float*)d_in[4];
  const float* bk = (const float*)d_in[5];
  const float* Wv = (const float*)d_in[6];
  const float* bv = (const float*)d_in[7];
  const float* Wo = (const float*)d_in[8];
  const float* bo = (const float*)d_in[9];
  float* out = (float*)d_out;

  const int NE = 8192 * 768;
  const int WE = 768 * 768;
  unsigned short* ws   = (unsigned short*)d_ws;
  unsigned short* xb   = ws;               // x bf16 [8192][768]
  unsigned short* wqkv = xb + NE;          // [2304][768]
  unsigned short* wob  = wqkv + 3 * WE;    // [768][768]
  unsigned short* qb   = wob + WE;         // Q|K|V each [24][4096][64]
  unsigned short* ctxb = qb + 3 * NE;      // ctx bf16 [8192][768]

  cvt_kernel<<<dim3(2048), 256, 0, stream>>>(x, xb, NE / 8);
  cvt_kernel<<<dim3(288), 256, 0, stream>>>(Wq, wqkv, WE / 8);
  cvt_kernel<<<dim3(288), 256, 0, stream>>>(Wk, wqkv + WE, WE / 8);
  cvt_kernel<<<dim3(288), 256, 0, stream>>>(Wv, wqkv + 2 * WE, WE / 8);
  cvt_kernel<<<dim3(288), 256, 0, stream>>>(Wo, wob, WE / 8);

  gemm_bt<0><<<dim3(18, 64), 256, 0, stream>>>(xb, wqkv, 768, bq, bk, bv, qb, nullptr);
  attn_kernel<<<dim3(32, 24), 256, 0, stream>>>(qb, qb + NE, qb + 2 * NE, mask, ctxb);
  gemm_bt<1><<<dim3(6, 64), 256, 0, stream>>>(ctxb, wob, 768, bo, nullptr, nullptr,
                                              nullptr, out);
}